// Round 18
// baseline (148.371 us; speedup 1.0000x reference)
//
#include <hip/hip_runtime.h>
#include <math.h>

// ---------------------------------------------------------------------------
// Problem: B=64 batches. a_p = a@W1^T + b1 [64,1024]; b_p = b@W2^T + b2.
// cost[b,i,j] = (a_p[b,i]-b_p[b,j])^2 ; DTW DP R[i,j]=cost+min(diag,up,left);
// out[b] = R[1023,1023].
// ---------------------------------------------------------------------------

#define L 1024
#define BATCH 64

// ---------------- GEMM: out[b,i] = sum_k X[b,k]*W[i,k] (+ bias) ------------
__global__ __launch_bounds__(256) void proj_kernel(
    const float* __restrict__ a, const float* __restrict__ b,
    const float* __restrict__ W1, const float* __restrict__ b1,
    const float* __restrict__ W2, const float* __restrict__ b2,
    float* __restrict__ ap, float* __restrict__ bp, int KC) {
  int part = blockIdx.x >> 7;
  int sub = blockIdx.x & 127;
  const float* X;
  const float* W;
  const float* bias;
  float* out;
  int i0;
  if (sub < 64) {
    X = a; W = W1; bias = b1; out = ap + part * BATCH * L; i0 = sub * 16;
  } else {
    X = b; W = W2; bias = b2; out = bp + part * BATCH * L; i0 = (sub - 64) * 16;
  }

  __shared__ float a_s[64][36];
  __shared__ float w_s[16][36];

  int tid = threadIdx.x;
  int lane_b = tid & 63;
  int iq = tid >> 6;

  float acc[4] = {0.f, 0.f, 0.f, 0.f};

  int kbeg = part * KC;
  int kend = kbeg + KC;
  for (int k0 = kbeg; k0 < kend; k0 += 32) {
    {
      int row = tid >> 2;
      int kl = (tid & 3) * 8;
      const float4* src = reinterpret_cast<const float4*>(&X[row * L + k0 + kl]);
      float4 v0 = src[0];
      float4 v1 = src[1];
      *reinterpret_cast<float4*>(&a_s[row][kl]) = v0;
      *reinterpret_cast<float4*>(&a_s[row][kl + 4]) = v1;
    }
    {
      int row = tid >> 4;
      int kl = (tid & 15) * 2;
      float2 v = *reinterpret_cast<const float2*>(&W[(i0 + row) * L + k0 + kl]);
      w_s[row][kl] = v.x;
      w_s[row][kl + 1] = v.y;
    }
    __syncthreads();
    #pragma unroll
    for (int kl = 0; kl < 32; kl += 4) {
      float4 av = *reinterpret_cast<const float4*>(&a_s[lane_b][kl]);
      #pragma unroll
      for (int m = 0; m < 4; ++m) {
        float4 wv = *reinterpret_cast<const float4*>(&w_s[iq * 4 + m][kl]);
        acc[m] += av.x * wv.x + av.y * wv.y + av.z * wv.z + av.w * wv.w;
      }
    }
    __syncthreads();
  }

  #pragma unroll
  for (int m = 0; m < 4; ++m) {
    int i = i0 + iq * 4 + m;
    float bv = (part == 0) ? bias[i] : 0.f;
    out[lane_b * L + i] = acc[m] + bv;
  }
}

// ---------------- DTW: 2 batches per lane (ILP=2), 4 waves/block -----------
// Block handles batches bA=2*blk, bB=2*blk+1 with IDENTICAL systolic
// geometry: lane (w,t) owns CPL=4 columns from (w*64+t)*4 of BOTH batches;
// delay D = w*OFF + t rows; step s processes row i = s-D of both.
// Rationale (R17 discriminator): with 1 wave/SIMD and in-order issue the
// step body executes near-serially (~6.5 cyc/instr incl. hazards) — five
// step-body variants all land at per-step ~ 6.5 x instr-count. Two
// INDEPENDENT DP chains interleave in the issue stream, so chain B's
// instructions fill chain A's dependency stalls: per-step cost for TWO
// batches ~ issue-bound (~40 instrs) instead of 2x serial.
// Transport per chain is R15-verbatim (untied bound_ctrl=1 DPP + cndmask;
// per-group exec-masked ring read/write; per-group wave-0 ringchunk
// re-init). Ring/slot math unchanged; ring/ap arrays duplicated per batch.
// GAP = OFF-63 = 32 = KBAR: production one barrier-ordered group before
// consumption; slot reuse distance 2 groups. Ramp/drain garbage discarded
// by the shared row-validity predicate (same D for both chains).

#define NW 4
#define CPL 4
#define KBAR 32
#define OFF 95                       // 64 + 31 -> GAP = 32
#define DMAX (OFF * (NW - 1) + 63)   // 348
#define NG 43                        // ceil((L + DMAX) / KBAR)
#define NSTEPS (NG * KBAR)           // 1376
#define APPAD (DMAX + NSTEPS + 64)   // 1788

__device__ __forceinline__ float dpp_shr1_z(float v) {
  // wave_shr:1, bound_ctrl=1: lane i <- lane i-1; lane 0 <- 0. One instr.
  int r = __builtin_amdgcn_update_dpp(0, __float_as_int(v), 0x138, 0xf, 0xf,
                                      true);
  return __int_as_float(r);
}

__device__ __forceinline__ float dpp_shl1_z(float v) {
  // wave_shl:1, bound_ctrl=1: lane i <- lane i+1; lane 63 <- 0. One instr.
  int r = __builtin_amdgcn_update_dpp(0, __float_as_int(v), 0x130, 0xf, 0xf,
                                      true);
  return __int_as_float(r);
}

__device__ __forceinline__ float min3f(float x, float y, float z) {
  float r;
  asm("v_min3_f32 %0, %1, %2, %3" : "=v"(r) : "v"(x), "v"(y), "v"(z));
  return r;
}

__global__ __launch_bounds__(256, 1) void dtw_kernel(
    const float* __restrict__ app, const float* __restrict__ bpp,
    float* __restrict__ out, int parts) {
  const int bA = blockIdx.x * 2;
  const int bB = bA + 1;
  const int tid = threadIdx.x;
  const int w = tid >> 6;
  const int t = tid & 63;
  const int woff = w * OFF;
  const int D = woff + t;
  const float INF = INFINITY;

  __shared__ float ap_pad[2][APPAD];
  __shared__ float ring[2][NW - 1][64];

  // ap_pad[q][DMAX + i] = sum_p ap_part[p][bq,i]; zero skirts.
  for (int idx = tid; idx < APPAD; idx += 256) {
    int src = idx - DMAX;
    float vA = 0.f, vB = 0.f;
    if ((unsigned)src < (unsigned)L) {
      vA = app[bA * L + src];
      vB = app[bB * L + src];
      for (int p = 1; p < parts; ++p) {
        vA += app[p * BATCH * L + bA * L + src];
        vB += app[p * BATCH * L + bB * L + src];
      }
    }
    ap_pad[0][idx] = vA;
    ap_pad[1][idx] = vB;
  }

  float4 bvA = *reinterpret_cast<const float4*>(&bpp[bA * L + tid * CPL]);
  float4 bvB = *reinterpret_cast<const float4*>(&bpp[bB * L + tid * CPL]);
  for (int p = 1; p < parts; ++p) {
    float4 uA = *reinterpret_cast<const float4*>(
        &bpp[p * BATCH * L + bA * L + tid * CPL]);
    float4 uB = *reinterpret_cast<const float4*>(
        &bpp[p * BATCH * L + bB * L + tid * CPL]);
    bvA.x += uA.x; bvA.y += uA.y; bvA.z += uA.z; bvA.w += uA.w;
    bvB.x += uB.x; bvB.y += uB.y; bvB.z += uB.z; bvB.w += uB.w;
  }
  const float bpv0A = bvA.x, bpv1A = bvA.y, bpv2A = bvA.z, bpv3A = bvA.w;
  const float bpv0B = bvB.x, bpv1B = bvB.y, bpv2B = bvB.z, bpv3B = bvB.w;

  float p0A = INF, p1A = INF, p2A = INF, p3A = INF;
  float p0B = INF, p1B = INF, p2B = INF, p3B = INF;
  float rightA = INF, prev_leftA = INF, vprodA = INF, ringchunkA = INF;
  float rightB = INF, prev_leftB = INF, vprodB = INF, ringchunkB = INF;
  const bool lane0 = (t == 0);
  const bool lane63 = (t == 63);
  const float* aplA = &ap_pad[0][DMAX - D];  // aplA[s] == ap[bA, s-D]
  const float* aplB = &ap_pad[1][DMAX - D];

  __syncthreads();

  // One 32-step group; both chains advance together (same D -> same PRED).
#define DTW_GROUP(s0v, PRED, FIRSTG)                                         \
  {                                                                          \
    const int s0 = (s0v);                                                    \
    float apfA[KBAR], apfB[KBAR];                                            \
    _Pragma("unroll")                                                        \
    for (int k = 0; k < KBAR; ++k) {                                         \
      apfA[k] = aplA[s0 + k];                                                \
      apfB[k] = aplB[s0 + k];                                                \
    }                                                                        \
    if (w == 0) {                                                            \
      ringchunkA = ((FIRSTG) && lane0) ? 0.f : INF;                          \
      ringchunkB = ((FIRSTG) && lane0) ? 0.f : INF;                          \
    } else if (t < KBAR) {                                                   \
      ringchunkA = ring[0][w - 1][(s0 - woff + t) & 63];                     \
      ringchunkB = ring[1][w - 1][(s0 - woff + t) & 63];                     \
    }                                                                        \
    _Pragma("unroll")                                                        \
    for (int k = 0; k < KBAR; ++k) {                                         \
      float shiftedA = dpp_shr1_z(rightA);                                   \
      float shiftedB = dpp_shr1_z(rightB);                                   \
      float leftA = lane0 ? ringchunkA : shiftedA;                           \
      float leftB = lane0 ? ringchunkB : shiftedB;                           \
      ringchunkA = dpp_shl1_z(ringchunkA);                                   \
      ringchunkB = dpp_shl1_z(ringchunkB);                                   \
      int ii = s0 + k - D;                                                   \
      if (!(PRED) || ((unsigned)ii < (unsigned)L)) {                         \
        float dprevA = prev_leftA;                                           \
        float dprevB = prev_leftB;                                           \
        if ((FIRSTG) && k == 1 && w == 0 && t == 0) {                        \
          dprevA = INF;                                                      \
          dprevB = INF;                                                      \
        }                                                                    \
        prev_leftA = leftA;                                                  \
        prev_leftB = leftB;                                                  \
        float apvA = apfA[k], apvB = apfB[k];                                \
        float d0A = apvA - bpv0A, d1A = apvA - bpv1A;                        \
        float d2A = apvA - bpv2A, d3A = apvA - bpv3A;                        \
        float d0B = apvB - bpv0B, d1B = apvB - bpv1B;                        \
        float d2B = apvB - bpv2B, d3B = apvB - bpv3B;                        \
        float xA = leftA, xB = leftB, bbA, bbB;                              \
        bbA = min3f(p0A, dprevA, xA); xA = __builtin_fmaf(d0A, d0A, bbA);    \
        bbB = min3f(p0B, dprevB, xB); xB = __builtin_fmaf(d0B, d0B, bbB);    \
        dprevA = p0A; p0A = xA;                                              \
        dprevB = p0B; p0B = xB;                                              \
        bbA = min3f(p1A, dprevA, xA); xA = __builtin_fmaf(d1A, d1A, bbA);    \
        bbB = min3f(p1B, dprevB, xB); xB = __builtin_fmaf(d1B, d1B, bbB);    \
        dprevA = p1A; p1A = xA;                                              \
        dprevB = p1B; p1B = xB;                                              \
        bbA = min3f(p2A, dprevA, xA); xA = __builtin_fmaf(d2A, d2A, bbA);    \
        bbB = min3f(p2B, dprevB, xB); xB = __builtin_fmaf(d2B, d2B, bbB);    \
        dprevA = p2A; p2A = xA;                                              \
        dprevB = p2B; p2B = xB;                                              \
        bbA = min3f(p3A, dprevA, xA); xA = __builtin_fmaf(d3A, d3A, bbA);    \
        bbB = min3f(p3B, dprevB, xB); xB = __builtin_fmaf(d3B, d3B, bbB);    \
        p3A = xA; rightA = xA;                                               \
        p3B = xB; rightB = xB;                                               \
      }                                                                      \
      vprodA = dpp_shl1_z(vprodA);                                           \
      vprodB = dpp_shl1_z(vprodB);                                           \
      vprodA = lane63 ? rightA : vprodA;                                     \
      vprodB = lane63 ? rightB : vprodB;                                     \
    }                                                                        \
    if (w < NW - 1 && t >= 64 - KBAR) {                                      \
      ring[0][w][(s0 + t - woff - (63 + KBAR)) & 63] = vprodA;               \
      ring[1][w][(s0 + t - woff - (63 + KBAR)) & 63] = vprodB;               \
    }                                                                        \
    __syncthreads();                                                         \
  }

  // Ramp: groups 0..10 (steps 0..351 cover s < DMAX=348, predicated).
  for (int g = 0; g < 11; ++g) DTW_GROUP(g * KBAR, true, g == 0);
  // Steady: groups 11..31 (steps 352..1023; every lane's i in [0,L)).
  for (int g = 11; g < 32; ++g) DTW_GROUP(g * KBAR, false, false);
  // Drain: groups 32..42 (steps 1024..1375; last active step 1371).
  for (int g = 32; g < NG; ++g) DTW_GROUP(g * KBAR, true, false);
#undef DTW_GROUP

  if (tid == NW * 64 - 1) {
    out[bA] = rightA;  // R[1023,1023] of batch A
    out[bB] = rightB;  // R[1023,1023] of batch B
  }
}

extern "C" void kernel_launch(void* const* d_in, const int* in_sizes, int n_in,
                              void* d_out, int out_size, void* d_ws, size_t ws_size,
                              hipStream_t stream) {
  const float* a  = (const float*)d_in[0];
  const float* b  = (const float*)d_in[1];
  const float* W1 = (const float*)d_in[2];
  const float* b1 = (const float*)d_in[3];
  const float* W2 = (const float*)d_in[4];
  const float* b2 = (const float*)d_in[5];
  float* out = (float*)d_out;

  size_t per_part = (size_t)2 * BATCH * L * sizeof(float);
  int parts = 1;
  if (ws_size >= 4 * per_part) parts = 4;
  else if (ws_size >= 2 * per_part) parts = 2;

  float* ap = (float*)d_ws;                    // parts x [BATCH, L]
  float* bp = ap + (size_t)parts * BATCH * L;  // parts x [BATCH, L]

  proj_kernel<<<128 * parts, 256, 0, stream>>>(a, b, W1, b1, W2, b2,
                                               ap, bp, L / parts);
  dtw_kernel<<<BATCH / 2, 256, 0, stream>>>(ap, bp, out, parts);
}

// Round 19
// 122.018 us; speedup vs baseline: 1.2160x; 1.2160x over previous
//
#include <hip/hip_runtime.h>
#include <math.h>

// ---------------------------------------------------------------------------
// Problem: B=64 batches. a_p = a@W1^T + b1 [64,1024]; b_p = b@W2^T + b2.
// cost[b,i,j] = (a_p[b,i]-b_p[b,j])^2 ; DTW DP R[i,j]=cost+min(diag,up,left);
// out[b] = R[1023,1023].
// ---------------------------------------------------------------------------

#define L 1024
#define BATCH 64

// ---------------- GEMM: out[b,i] = sum_k X[b,k]*W[i,k] (+ bias) ------------
__global__ __launch_bounds__(256) void proj_kernel(
    const float* __restrict__ a, const float* __restrict__ b,
    const float* __restrict__ W1, const float* __restrict__ b1,
    const float* __restrict__ W2, const float* __restrict__ b2,
    float* __restrict__ ap, float* __restrict__ bp, int KC) {
  int part = blockIdx.x >> 7;
  int sub = blockIdx.x & 127;
  const float* X;
  const float* W;
  const float* bias;
  float* out;
  int i0;
  if (sub < 64) {
    X = a; W = W1; bias = b1; out = ap + part * BATCH * L; i0 = sub * 16;
  } else {
    X = b; W = W2; bias = b2; out = bp + part * BATCH * L; i0 = (sub - 64) * 16;
  }

  __shared__ float a_s[64][36];
  __shared__ float w_s[16][36];

  int tid = threadIdx.x;
  int lane_b = tid & 63;
  int iq = tid >> 6;

  float acc[4] = {0.f, 0.f, 0.f, 0.f};

  int kbeg = part * KC;
  int kend = kbeg + KC;
  for (int k0 = kbeg; k0 < kend; k0 += 32) {
    {
      int row = tid >> 2;
      int kl = (tid & 3) * 8;
      const float4* src = reinterpret_cast<const float4*>(&X[row * L + k0 + kl]);
      float4 v0 = src[0];
      float4 v1 = src[1];
      *reinterpret_cast<float4*>(&a_s[row][kl]) = v0;
      *reinterpret_cast<float4*>(&a_s[row][kl + 4]) = v1;
    }
    {
      int row = tid >> 4;
      int kl = (tid & 15) * 2;
      float2 v = *reinterpret_cast<const float2*>(&W[(i0 + row) * L + k0 + kl]);
      w_s[row][kl] = v.x;
      w_s[row][kl + 1] = v.y;
    }
    __syncthreads();
    #pragma unroll
    for (int kl = 0; kl < 32; kl += 4) {
      float4 av = *reinterpret_cast<const float4*>(&a_s[lane_b][kl]);
      #pragma unroll
      for (int m = 0; m < 4; ++m) {
        float4 wv = *reinterpret_cast<const float4*>(&w_s[iq * 4 + m][kl]);
        acc[m] += av.x * wv.x + av.y * wv.y + av.z * wv.z + av.w * wv.w;
      }
    }
    __syncthreads();
  }

  #pragma unroll
  for (int m = 0; m < 4; ++m) {
    int i = i0 + iq * 4 + m;
    float bv = (part == 0) ? bias[i] : 0.f;
    out[lane_b * L + i] = acc[m] + bv;
  }
}

// ---------------- DTW: 2 batches per block, one 4-wave pipeline each -------
// 512 threads = 8 waves. Waves 0-3 = pipeline for batch bA; waves 4-7 =
// pipeline for batch bB. Each pipeline is R15-VERBATIM: lane (wl,t) owns
// CPL=4 columns from (wl*64+t)*4; delay D = wl*OFF + t rows; step s
// processes row i = s-D; untied bound_ctrl=1 DPP transport + per-group
// exec-masked ring read/write; per-group wave-0 ringchunk re-init.
// WHY (R18 discriminator): each SIMD now hosts 2 co-resident waves with
// INDEPENDENT instruction streams (one per batch). HW round-robin issue
// fills one wave's dependency/hazard stalls with the other's instructions —
// no single wave's stream is inflated (R18's lane-ILP mistake) and NSTEPS
// stays 1376 (R7's NW=8 mistake grew it to 1760). The two pipelines share
// the per-group __syncthreads(); identical structure -> minimal skew.
// GAP = OFF-63 = 32 = KBAR: production one barrier-ordered group before
// consumption; ring slot reuse distance 2 groups; ramp/drain garbage
// discarded by the row-validity predicate.

#define NW 4
#define CPL 4
#define KBAR 32
#define OFF 95                       // 64 + 31 -> GAP = 32
#define DMAX (OFF * (NW - 1) + 63)   // 348
#define NG 43                        // ceil((L + DMAX) / KBAR)
#define NSTEPS (NG * KBAR)           // 1376
#define APPAD (DMAX + NSTEPS + 64)   // 1788

__device__ __forceinline__ float dpp_shr1_z(float v) {
  // wave_shr:1, bound_ctrl=1: lane i <- lane i-1; lane 0 <- 0. One instr.
  int r = __builtin_amdgcn_update_dpp(0, __float_as_int(v), 0x138, 0xf, 0xf,
                                      true);
  return __int_as_float(r);
}

__device__ __forceinline__ float dpp_shl1_z(float v) {
  // wave_shl:1, bound_ctrl=1: lane i <- lane i+1; lane 63 <- 0. One instr.
  int r = __builtin_amdgcn_update_dpp(0, __float_as_int(v), 0x130, 0xf, 0xf,
                                      true);
  return __int_as_float(r);
}

__device__ __forceinline__ float min3f(float x, float y, float z) {
  float r;
  asm("v_min3_f32 %0, %1, %2, %3" : "=v"(r) : "v"(x), "v"(y), "v"(z));
  return r;
}

__global__ __launch_bounds__(512, 1) void dtw_kernel(
    const float* __restrict__ app, const float* __restrict__ bpp,
    float* __restrict__ out, int parts) {
  const int tid = threadIdx.x;
  const int q = tid >> 8;           // 0: batch A pipeline, 1: batch B
  const int wl = (tid >> 6) & 3;    // wave within pipeline
  const int t = tid & 63;
  const int bq = blockIdx.x * 2 + q;
  const int woff = wl * OFF;
  const int D = woff + t;
  const float INF = INFINITY;

  __shared__ float ap_pad[2][APPAD];
  __shared__ float ring[2][NW - 1][64];

  // ap_pad[qq][DMAX + i] = sum_p ap_part[p][b(qq),i]; zero skirts.
  {
    const int bA = blockIdx.x * 2;
    for (int idx = tid; idx < APPAD; idx += 512) {
      int src = idx - DMAX;
      float vA = 0.f, vB = 0.f;
      if ((unsigned)src < (unsigned)L) {
        vA = app[bA * L + src];
        vB = app[(bA + 1) * L + src];
        for (int p = 1; p < parts; ++p) {
          vA += app[p * BATCH * L + bA * L + src];
          vB += app[p * BATCH * L + (bA + 1) * L + src];
        }
      }
      ap_pad[0][idx] = vA;
      ap_pad[1][idx] = vB;
    }
  }

  // My 4 columns of my batch: col_base = (wl*64+t)*4 = (tid&255)*4.
  const int colb = (tid & 255) * CPL;
  float4 bv = *reinterpret_cast<const float4*>(&bpp[bq * L + colb]);
  for (int p = 1; p < parts; ++p) {
    float4 u = *reinterpret_cast<const float4*>(
        &bpp[p * BATCH * L + bq * L + colb]);
    bv.x += u.x; bv.y += u.y; bv.z += u.z; bv.w += u.w;
  }
  const float bpv0 = bv.x, bpv1 = bv.y, bpv2 = bv.z, bpv3 = bv.w;

  float p0 = INF, p1 = INF, p2 = INF, p3 = INF;  // prev-row cells
  float right = INF, prev_left = INF;
  float vprod = INF;
  float ringchunk = INF;  // set per group below
  const bool lane0 = (t == 0);
  const bool lane63 = (t == 63);
  const float* apl = &ap_pad[q][DMAX - D];  // apl[s] == ap[bq, s-D]

  __syncthreads();

  // One 32-step group. PRED: row-range predicate (ramp/drain). FIRSTG: the
  // first group seeds R[0,0]'s left and carries the one-time diag fixup.
#define DTW_GROUP(s0v, PRED, FIRSTG)                                         \
  {                                                                          \
    const int s0 = (s0v);                                                    \
    float apf[KBAR];                                                         \
    _Pragma("unroll")                                                        \
    for (int k = 0; k < KBAR; ++k) apf[k] = apl[s0 + k];                     \
    if (wl == 0)                                                             \
      ringchunk = ((FIRSTG) && lane0) ? 0.f : INF;                           \
    else if (t < KBAR)                                                       \
      ringchunk = ring[q][wl - 1][(s0 - woff + t) & 63];                     \
    _Pragma("unroll")                                                        \
    for (int k = 0; k < KBAR; ++k) {                                         \
      float shifted = dpp_shr1_z(right);                                     \
      float left = lane0 ? ringchunk : shifted;                              \
      ringchunk = dpp_shl1_z(ringchunk);                                     \
      int ii = s0 + k - D;                                                   \
      if (!(PRED) || ((unsigned)ii < (unsigned)L)) {                         \
        float dprev = prev_left;                                             \
        if ((FIRSTG) && k == 1 && wl == 0 && t == 0) dprev = INF;            \
        prev_left = left;                                                    \
        float apv = apf[k];                                                  \
        float d0 = apv - bpv0, d1 = apv - bpv1;                              \
        float d2 = apv - bpv2, d3 = apv - bpv3;                              \
        float x = left, bb;                                                  \
        bb = min3f(p0, dprev, x); x = __builtin_fmaf(d0, d0, bb);            \
        dprev = p0; p0 = x;                                                  \
        bb = min3f(p1, dprev, x); x = __builtin_fmaf(d1, d1, bb);            \
        dprev = p1; p1 = x;                                                  \
        bb = min3f(p2, dprev, x); x = __builtin_fmaf(d2, d2, bb);            \
        dprev = p2; p2 = x;                                                  \
        bb = min3f(p3, dprev, x); x = __builtin_fmaf(d3, d3, bb);            \
        p3 = x;                                                              \
        right = x;                                                           \
      }                                                                      \
      vprod = dpp_shl1_z(vprod);                                             \
      vprod = lane63 ? right : vprod;                                        \
    }                                                                        \
    if (wl < NW - 1 && t >= 64 - KBAR)                                       \
      ring[q][wl][(s0 + t - woff - (63 + KBAR)) & 63] = vprod;               \
    __syncthreads();                                                         \
  }

  // Ramp: groups 0..10 (steps 0..351 cover s < DMAX=348, predicated).
  for (int g = 0; g < 11; ++g) DTW_GROUP(g * KBAR, true, g == 0);
  // Steady: groups 11..31 (steps 352..1023; every lane's i in [0,L)).
  for (int g = 11; g < 32; ++g) DTW_GROUP(g * KBAR, false, false);
  // Drain: groups 32..42 (steps 1024..1375; last active step 1371).
  for (int g = 32; g < NG; ++g) DTW_GROUP(g * KBAR, true, false);
#undef DTW_GROUP

  // Last lane of each pipeline (tid 255 and 511) writes its batch's result.
  if ((tid & 255) == 255) out[bq] = right;  // R[1023,1023]
}

extern "C" void kernel_launch(void* const* d_in, const int* in_sizes, int n_in,
                              void* d_out, int out_size, void* d_ws, size_t ws_size,
                              hipStream_t stream) {
  const float* a  = (const float*)d_in[0];
  const float* b  = (const float*)d_in[1];
  const float* W1 = (const float*)d_in[2];
  const float* b1 = (const float*)d_in[3];
  const float* W2 = (const float*)d_in[4];
  const float* b2 = (const float*)d_in[5];
  float* out = (float*)d_out;

  size_t per_part = (size_t)2 * BATCH * L * sizeof(float);
  int parts = 1;
  if (ws_size >= 4 * per_part) parts = 4;
  else if (ws_size >= 2 * per_part) parts = 2;

  float* ap = (float*)d_ws;                    // parts x [BATCH, L]
  float* bp = ap + (size_t)parts * BATCH * L;  // parts x [BATCH, L]

  proj_kernel<<<128 * parts, 256, 0, stream>>>(a, b, W1, b1, W2, b2,
                                               ap, bp, L / parts);
  dtw_kernel<<<BATCH / 2, 512, 0, stream>>>(ap, bp, out, parts);
}

// Round 20
// 106.142 us; speedup vs baseline: 1.3979x; 1.1496x over previous
//
#include <hip/hip_runtime.h>
#include <math.h>

// ---------------------------------------------------------------------------
// Problem: B=64 batches. a_p = a@W1^T + b1 [64,1024]; b_p = b@W2^T + b2.
// cost[b,i,j] = (a_p[b,i]-b_p[b,j])^2 ; DTW DP R[i,j]=cost+min(diag,up,left);
// out[b] = R[1023,1023].
// ---------------------------------------------------------------------------

#define L 1024
#define BATCH 64

// ---------------- GEMM: out[b,i] = sum_k X[b,k]*W[i,k] (+ bias) ------------
__global__ __launch_bounds__(256) void proj_kernel(
    const float* __restrict__ a, const float* __restrict__ b,
    const float* __restrict__ W1, const float* __restrict__ b1,
    const float* __restrict__ W2, const float* __restrict__ b2,
    float* __restrict__ ap, float* __restrict__ bp, int KC) {
  int part = blockIdx.x >> 7;
  int sub = blockIdx.x & 127;
  const float* X;
  const float* W;
  const float* bias;
  float* out;
  int i0;
  if (sub < 64) {
    X = a; W = W1; bias = b1; out = ap + part * BATCH * L; i0 = sub * 16;
  } else {
    X = b; W = W2; bias = b2; out = bp + part * BATCH * L; i0 = (sub - 64) * 16;
  }

  __shared__ float a_s[64][36];
  __shared__ float w_s[16][36];

  int tid = threadIdx.x;
  int lane_b = tid & 63;
  int iq = tid >> 6;

  float acc[4] = {0.f, 0.f, 0.f, 0.f};

  int kbeg = part * KC;
  int kend = kbeg + KC;
  for (int k0 = kbeg; k0 < kend; k0 += 32) {
    {
      int row = tid >> 2;
      int kl = (tid & 3) * 8;
      const float4* src = reinterpret_cast<const float4*>(&X[row * L + k0 + kl]);
      float4 v0 = src[0];
      float4 v1 = src[1];
      *reinterpret_cast<float4*>(&a_s[row][kl]) = v0;
      *reinterpret_cast<float4*>(&a_s[row][kl + 4]) = v1;
    }
    {
      int row = tid >> 4;
      int kl = (tid & 15) * 2;
      float2 v = *reinterpret_cast<const float2*>(&W[(i0 + row) * L + k0 + kl]);
      w_s[row][kl] = v.x;
      w_s[row][kl + 1] = v.y;
    }
    __syncthreads();
    #pragma unroll
    for (int kl = 0; kl < 32; kl += 4) {
      float4 av = *reinterpret_cast<const float4*>(&a_s[lane_b][kl]);
      #pragma unroll
      for (int m = 0; m < 4; ++m) {
        float4 wv = *reinterpret_cast<const float4*>(&w_s[iq * 4 + m][kl]);
        acc[m] += av.x * wv.x + av.y * wv.y + av.z * wv.z + av.w * wv.w;
      }
    }
    __syncthreads();
  }

  #pragma unroll
  for (int m = 0; m < 4; ++m) {
    int i = i0 + iq * 4 + m;
    float bv = (part == 0) ? bias[i] : 0.f;
    out[lane_b * L + i] = acc[m] + bv;
  }
}

// ---------------- DTW: anti-diagonal wavefront, 4 waves/batch --------------
// Global lane g = w*64+t owns columns [4g, 4g+4). All 64 lanes of wave w
// jointly compute anti-diagonal d = s - 31*w at step s (NO per-lane skew).
// Cell (i=d-j, j): up = prev1[m] (diag d-1, same col), left = prev1[m-1]
// (diag d-1, col-1), diag = prev2[m-1] (diag d-2, col-1). The 4 slots are
// MUTUALLY INDEPENDENT -> per-step critical path = min3+fma (~10 cyc), vs
// the row-systolic 8-op serial chain (R6..R19 all ~138+ cyc/step). All DPP
// sources (prev1_3/prev2_3/A3) are >=1 step old -> off critical path.
// ap transport: lane g needs ap[d-4g-m] = 4-deep in-lane shift register
// A0..A3; A0 arrives via DPP from lane t-1's A3 (value ap[d-4g] exactly);
// lane 0 fed from a per-group-loaded walking apchunk. INF SKIRTS in ap_pad
// make every out-of-range cell compute to INF (INF-bp)^2 = INF -> NO
// ramp/drain predicates anywhere. Ring carries boundary x3 (col 256w-1)
// per diag; consumer derives both feeds: p1m1 <- v_{dc-1} (walked chunk),
// p2m1 <- v_{dc-2} (= previous step's feed, register copy).
// OFF=31: production->consumption = exactly 32 steps = one barrier-ordered
// group, and group read slots [s0-31w-1 .. +30] vs write slots
// [s0-31w+31 .. +62] are DISJOINT 32-slot halves mod 64 (no same-epoch
// race — OFF=34 would overlap 3 slots). Ring pre-INF'd so early reads are
// INF (also avoids NaN via INF*INF+garbage).
// Result: R[1023,1023] = x3 of (w=3, t=63) at d=2046 -> s = 2046+93 = 2139
// = group 66, k=27.

#define NW 4
#define CPL 4
#define KBAR 32
#define OFF 31
#define NG 67                        // groups 0..66; 2144 steps total
#define APOFF 864                    // covers min index -(256+OFF)*3 - ...
#define APPAD 3048                   // 864 + 2112+63+1 + pad

__device__ __forceinline__ float dpp_shr1_z(float v) {
  // wave_shr:1, bound_ctrl=1: lane i <- lane i-1; lane 0 <- 0. One instr.
  int r = __builtin_amdgcn_update_dpp(0, __float_as_int(v), 0x138, 0xf, 0xf,
                                      true);
  return __int_as_float(r);
}

__device__ __forceinline__ float dpp_shl1_z(float v) {
  // wave_shl:1, bound_ctrl=1: lane i <- lane i+1; lane 63 <- 0. One instr.
  int r = __builtin_amdgcn_update_dpp(0, __float_as_int(v), 0x130, 0xf, 0xf,
                                      true);
  return __int_as_float(r);
}

__device__ __forceinline__ float min3f(float x, float y, float z) {
  float r;
  asm("v_min3_f32 %0, %1, %2, %3" : "=v"(r) : "v"(x), "v"(y), "v"(z));
  return r;
}

__global__ __launch_bounds__(256, 1) void dtw_kernel(
    const float* __restrict__ app, const float* __restrict__ bpp,
    float* __restrict__ out, int parts) {
  const int b = blockIdx.x;
  const int tid = threadIdx.x;
  const int w = tid >> 6;
  const int t = tid & 63;
  const int woff = OFF * w;
  const float INF = INFINITY;

  __shared__ float ap_pad[APPAD];
  __shared__ float ring[NW - 1][64];

  // ap_pad[APOFF + i] = sum_p ap_part[p][b,i]; INF skirts (key: makes all
  // out-of-matrix cells evaluate to INF with no predicates).
  for (int idx = tid; idx < APPAD; idx += 256) {
    int src = idx - APOFF;
    float v = INF;
    if ((unsigned)src < (unsigned)L) {
      v = app[b * L + src];
      for (int p = 1; p < parts; ++p) v += app[p * BATCH * L + b * L + src];
    }
    ap_pad[idx] = v;
  }
  if (tid < (NW - 1) * 64) reinterpret_cast<float*>(ring)[tid] = INF;

  const int colb = tid * CPL;  // tid == g (global lane)
  float4 bv = *reinterpret_cast<const float4*>(&bpp[b * L + colb]);
  for (int p = 1; p < parts; ++p) {
    float4 u = *reinterpret_cast<const float4*>(
        &bpp[p * BATCH * L + b * L + colb]);
    bv.x += u.x; bv.y += u.y; bv.z += u.z; bv.w += u.w;
  }
  const float bpv0 = bv.x, bpv1 = bv.y, bpv2 = bv.z, bpv3 = bv.w;

  float p1_0 = INF, p1_1 = INF, p1_2 = INF, p1_3 = INF;  // diag d-1
  float p2_0 = INF, p2_1 = INF, p2_2 = INF, p2_3 = INF;  // diag d-2
  float A0 = INF, A1 = INF, A2 = INF, A3 = INF;          // ap shift regs
  float ringchunk = INF, feedprev = INF, vprod = INF, apchunk;
  float res = 0.f;
  const bool lane0 = (t == 0);
  const bool lane63 = (t == 63);
  const int apbase = APOFF + t - (256 + OFF) * w;  // lane-t group-load index

  __syncthreads();

#define DTW_GROUP(s0v, FIRSTG, LASTG)                                        \
  {                                                                          \
    const int s0 = (s0v);                                                    \
    apchunk = ap_pad[apbase + s0];                                           \
    if (w == 0)                                                              \
      ringchunk = INF;                                                       \
    else if (t < KBAR)                                                       \
      ringchunk = ring[w - 1][(s0 + t - woff - 1) & 63];                     \
    _Pragma("unroll")                                                        \
    for (int k = 0; k < KBAR; ++k) {                                         \
      float sh1 = dpp_shr1_z(p1_3);                                          \
      float sh2 = dpp_shr1_z(p2_3);                                          \
      float sha = dpp_shr1_z(A3);                                            \
      float p1m1 = lane0 ? ringchunk : sh1;                                  \
      float p2m1 = lane0 ? feedprev : sh2;                                   \
      if ((FIRSTG) && k == 0 && w == 0) p2m1 = lane0 ? 0.f : sh2;            \
      feedprev = ringchunk;                                                  \
      ringchunk = dpp_shl1_z(ringchunk);                                     \
      A3 = A2; A2 = A1; A1 = A0;                                             \
      A0 = lane0 ? apchunk : sha;                                            \
      apchunk = dpp_shl1_z(apchunk);                                         \
      float d0 = A0 - bpv0, d1 = A1 - bpv1;                                  \
      float d2 = A2 - bpv2, d3 = A3 - bpv3;                                  \
      float b0 = min3f(p1_0, p1m1, p2m1);                                    \
      float b1 = min3f(p1_1, p1_0, p2_0);                                    \
      float b2 = min3f(p1_2, p1_1, p2_1);                                    \
      float b3 = min3f(p1_3, p1_2, p2_2);                                    \
      float x0 = __builtin_fmaf(d0, d0, b0);                                 \
      float x1 = __builtin_fmaf(d1, d1, b1);                                 \
      float x2 = __builtin_fmaf(d2, d2, b2);                                 \
      float x3 = __builtin_fmaf(d3, d3, b3);                                 \
      p2_0 = p1_0; p2_1 = p1_1; p2_2 = p1_2; p2_3 = p1_3;                    \
      p1_0 = x0; p1_1 = x1; p1_2 = x2; p1_3 = x3;                            \
      vprod = dpp_shl1_z(vprod);                                             \
      vprod = lane63 ? x3 : vprod;                                           \
      if ((LASTG) && k == 27) res = x3;                                      \
    }                                                                        \
    if (w < NW - 1 && t >= 64 - KBAR)                                        \
      ring[w][(s0 + t - 32 - woff) & 63] = vprod;                            \
    __syncthreads();                                                         \
  }

  DTW_GROUP(0, true, false);
  for (int g = 1; g < NG - 1; ++g) DTW_GROUP(g * KBAR, false, false);
  DTW_GROUP((NG - 1) * KBAR, false, true);
#undef DTW_GROUP

  if (w == NW - 1 && t == 63) out[b] = res;  // R[1023,1023]
}

extern "C" void kernel_launch(void* const* d_in, const int* in_sizes, int n_in,
                              void* d_out, int out_size, void* d_ws, size_t ws_size,
                              hipStream_t stream) {
  const float* a  = (const float*)d_in[0];
  const float* b  = (const float*)d_in[1];
  const float* W1 = (const float*)d_in[2];
  const float* b1 = (const float*)d_in[3];
  const float* W2 = (const float*)d_in[4];
  const float* b2 = (const float*)d_in[5];
  float* out = (float*)d_out;

  size_t per_part = (size_t)2 * BATCH * L * sizeof(float);
  int parts = 1;
  if (ws_size >= 4 * per_part) parts = 4;
  else if (ws_size >= 2 * per_part) parts = 2;

  float* ap = (float*)d_ws;                    // parts x [BATCH, L]
  float* bp = ap + (size_t)parts * BATCH * L;  // parts x [BATCH, L]

  proj_kernel<<<128 * parts, 256, 0, stream>>>(a, b, W1, b1, W2, b2,
                                               ap, bp, L / parts);
  dtw_kernel<<<BATCH, 256, 0, stream>>>(ap, bp, out, parts);
}